// Round 9
// baseline (279.584 us; speedup 1.0000x reference)
//
#include <hip/hip_runtime.h>
#include <math.h>

// Problem constants (fixed by the reference): B=16, C=9, H=W=512.
#define NCLS 9
#define NB 16
#define HW (512 * 512)          // labels per sample = 262144
#define NBLK_HIST 512           // 32 hist blocks per sample
#define BLKS_PER_SAMPLE 32
#define N4 (NB * NCLS * HW / 4) // 9437184 float4s
// Scale kernel geometry: 4 float4s/thread, 1024 float4s/block -> 9216 blocks.
// A (b,c) plane is 65536 float4s = exactly 64 blocks -> plane is block-uniform.
#define SCALE_BLOCKS (N4 / 1024)

// Native vector type: __builtin_nontemporal_store requires a scalar/native
// vector, not HIP's float4 class (R8 compile error).
typedef float vfloat4 __attribute__((ext_vector_type(4)));

// ---------------------------------------------------------------------------
// Kernel 1: per-block partial histograms -> partial[512][9] (fully written,
// no zero-init, no atomics). 512 blocks x 256 threads, 32 labels/thread.
// ---------------------------------------------------------------------------
__global__ void __launch_bounds__(256) hist_kernel(const int* __restrict__ labels,
                                                   int* __restrict__ partial) {
    const int tid = blockIdx.x * 256 + threadIdx.x;
    const int4* l4 = (const int4*)labels;
    const int base = tid * 8;           // int4 index

    int4 v[8];
#pragma unroll
    for (int j = 0; j < 8; ++j) v[j] = l4[base + j];

    int cnt[NCLS];
#pragma unroll
    for (int c = 0; c < NCLS; ++c) cnt[c] = 0;
#pragma unroll
    for (int j = 0; j < 8; ++j) {
#pragma unroll
        for (int c = 0; c < NCLS; ++c) {
            cnt[c] += (v[j].x == c) + (v[j].y == c) + (v[j].z == c) + (v[j].w == c);
        }
    }

    __shared__ int lds[4][NCLS];        // 4 waves per block
    const int wave = threadIdx.x >> 6;
    const int lane = threadIdx.x & 63;
#pragma unroll
    for (int c = 0; c < NCLS; ++c) {
        int s = cnt[c];
#pragma unroll
        for (int off = 32; off > 0; off >>= 1) s += __shfl_down(s, off);
        if (lane == 0) lds[wave][c] = s;
    }
    __syncthreads();
    if (threadIdx.x < NCLS) {
        const int c = threadIdx.x;
        partial[blockIdx.x * NCLS + c] =
            lds[0][c] + lds[1][c] + lds[2][c] + lds[3][c];
    }
}

// ---------------------------------------------------------------------------
// Kernel 2: weights from partials. One block, 192 threads (144 active).
// Thread t=(b,c) reduces this sample's 32 partials per class (L2-hot) and
// redundantly computes per-sample stats. Matches the numpy reference:
//   p = h/total; logh = (h>0) ? -log(p) : 0
//   mean/std over bins with h>0 (population variance, ddof=0)
//   weight = (logh != 0) ? (logh-mean)/std*0.1 + 1.0 : 1.0
// ---------------------------------------------------------------------------
__global__ void __launch_bounds__(192) weight_kernel(const int* __restrict__ partial,
                                                     float* __restrict__ weight) {
    const int t = threadIdx.x;
    if (t >= NB * NCLS) return;
    const int b = t / NCLS;
    const int c = t % NCLS;

    float h[NCLS];
    float total = 0.f;
#pragma unroll
    for (int k = 0; k < NCLS; ++k) {
        const int* p = partial + b * (BLKS_PER_SAMPLE * NCLS) + k;
        int s = 0;
#pragma unroll
        for (int j = 0; j < BLKS_PER_SAMPLE; ++j) s += p[j * NCLS];
        h[k] = (float)s;
        total += h[k];
    }

    float logh[NCLS];
    float cntbins = 0.f, sum = 0.f;
#pragma unroll
    for (int k = 0; k < NCLS; ++k) {
        float p = h[k] / total;
        float lg = (h[k] > 0.f) ? -logf(p) : 0.f;
        logh[k] = lg;
        if (h[k] > 0.f) { cntbins += 1.f; sum += lg; }
    }
    const float mean = sum / cntbins;
    float var = 0.f;
#pragma unroll
    for (int k = 0; k < NCLS; ++k) {
        if (h[k] > 0.f) {
            float d = logh[k] - mean;
            var += d * d;
        }
    }
    var /= cntbins;
    const float stdv = sqrtf(var);

    const float lc = logh[c];
    weight[t] = (lc != 0.f) ? (lc - mean) / stdv * 0.1f + 1.0f : 1.0f;
}

// ---------------------------------------------------------------------------
// Kernel 3: out = preds * weight. 9216 blocks x 256 threads, 4 float4s each.
// Block covers 1024 consecutive float4s; plane = blockIdx>>6 is BLOCK-UNIFORM
// -> single scalar weight load, no LDS, no barrier. 4 loads issued before the
// 4 mult+store pairs (compiler-scheduled, not SGB-pinned — R4 lesson).
// Stores are non-temporal: out is never re-read, so don't let its 147 MB
// evict preds' L3 residency (R5 FETCH=74MB shows preds is half-L3-resident).
// ---------------------------------------------------------------------------
__global__ void __launch_bounds__(256) scale_kernel(const vfloat4* __restrict__ in,
                                                    const float* __restrict__ weight,
                                                    vfloat4* __restrict__ out) {
    const float w = weight[blockIdx.x >> 6];        // block-uniform -> s_load
    const int i = blockIdx.x * 1024 + threadIdx.x;  // 4 slots: i + k*256

    vfloat4 v0 = in[i];
    vfloat4 v1 = in[i + 256];
    vfloat4 v2 = in[i + 512];
    vfloat4 v3 = in[i + 768];

    v0 *= w;
    v1 *= w;
    v2 *= w;
    v3 *= w;

    __builtin_nontemporal_store(v0, &out[i]);
    __builtin_nontemporal_store(v1, &out[i + 256]);
    __builtin_nontemporal_store(v2, &out[i + 512]);
    __builtin_nontemporal_store(v3, &out[i + 768]);
}

extern "C" void kernel_launch(void* const* d_in, const int* in_sizes, int n_in,
                              void* d_out, int out_size, void* d_ws, size_t ws_size,
                              hipStream_t stream) {
    const float* preds = (const float*)d_in[0];   // [16,9,512,512] f32
    const int* labels = (const int*)d_in[1];      // [16,512,512] i32
    float* out = (float*)d_out;

    // Workspace: partial[512][9] ints | weight[144] floats (both fully
    // overwritten every call -> no zero-init needed on poisoned ws).
    int* partial = (int*)d_ws;
    float* weight = (float*)((char*)d_ws + NBLK_HIST * NCLS * sizeof(int));

    hist_kernel<<<NBLK_HIST, 256, 0, stream>>>(labels, partial);
    weight_kernel<<<1, 192, 0, stream>>>(partial, weight);
    scale_kernel<<<SCALE_BLOCKS, 256, 0, stream>>>(
        (const vfloat4*)preds, weight, (vfloat4*)out);
}

// Round 10
// 275.622 us; speedup vs baseline: 1.0144x; 1.0144x over previous
//
#include <hip/hip_runtime.h>
#include <math.h>

// Problem constants (fixed by the reference): B=16, C=9, H=W=512.
#define NCLS 9
#define NB 16
#define HW (512 * 512)          // labels per sample = 262144
#define NBLK_HIST 512           // 32 hist blocks per sample
#define BLKS_PER_SAMPLE 32
#define N4 (NB * NCLS * HW / 4) // 9437184 float4s
// Scale kernel geometry: 4 float4s/thread, 1024 float4s/block -> 9216 blocks.
// A (b,c) plane is 65536 float4s = exactly 64 blocks -> plane is block-uniform.
#define SCALE_BLOCKS (N4 / 1024)

// Native vector type: __builtin_nontemporal_store requires a scalar/native
// vector, not HIP's float4 class (R8 compile error).
typedef float vfloat4 __attribute__((ext_vector_type(4)));

// ---------------------------------------------------------------------------
// Kernel 1: per-block partial histograms -> partial[512][9] (fully written,
// no zero-init, no atomics). 512 blocks x 256 threads, 32 labels/thread.
// ---------------------------------------------------------------------------
__global__ void __launch_bounds__(256) hist_kernel(const int* __restrict__ labels,
                                                   int* __restrict__ partial) {
    const int tid = blockIdx.x * 256 + threadIdx.x;
    const int4* l4 = (const int4*)labels;
    const int base = tid * 8;           // int4 index

    int4 v[8];
#pragma unroll
    for (int j = 0; j < 8; ++j) v[j] = l4[base + j];

    int cnt[NCLS];
#pragma unroll
    for (int c = 0; c < NCLS; ++c) cnt[c] = 0;
#pragma unroll
    for (int j = 0; j < 8; ++j) {
#pragma unroll
        for (int c = 0; c < NCLS; ++c) {
            cnt[c] += (v[j].x == c) + (v[j].y == c) + (v[j].z == c) + (v[j].w == c);
        }
    }

    __shared__ int lds[4][NCLS];        // 4 waves per block
    const int wave = threadIdx.x >> 6;
    const int lane = threadIdx.x & 63;
#pragma unroll
    for (int c = 0; c < NCLS; ++c) {
        int s = cnt[c];
#pragma unroll
        for (int off = 32; off > 0; off >>= 1) s += __shfl_down(s, off);
        if (lane == 0) lds[wave][c] = s;
    }
    __syncthreads();
    if (threadIdx.x < NCLS) {
        const int c = threadIdx.x;
        partial[blockIdx.x * NCLS + c] =
            lds[0][c] + lds[1][c] + lds[2][c] + lds[3][c];
    }
}

// ---------------------------------------------------------------------------
// Kernel 2 (fused): weight prologue + stream scale. 9216 blocks x 256 thr,
// 4 float4s each; plane p = blockIdx>>6 is BLOCK-UNIFORM.
// Prologue (hidden under the 4 in-flight HBM loads):
//   t<9:  h[t] = sum of this sample's 32 partials (L2-hot)  -> hsm
//   t<9:  logh[t] = (h>0) ? -log(h/total) : 0               -> lsm (9 logf/blk)
//   all:  stats from LDS (no logf): mean/std over bins with h>0 (ddof=0),
//         w = (logh[c]!=0) ? (logh[c]-mean)/std*0.1+1 : 1    [matches numpy]
// Stores non-temporal: out is never re-read; don't evict preds' L3 residency.
// ---------------------------------------------------------------------------
__global__ void __launch_bounds__(256) fused_scale_kernel(
        const int* __restrict__ partial,
        const vfloat4* __restrict__ in,
        vfloat4* __restrict__ out) {
    const int t = threadIdx.x;
    const int p = blockIdx.x >> 6;                  // plane 0..143
    const int i = blockIdx.x * 1024 + t;            // 4 slots: i + k*256

    // Issue the streaming loads FIRST; prologue hides under their latency.
    vfloat4 v0 = in[i];
    vfloat4 v1 = in[i + 256];
    vfloat4 v2 = in[i + 512];
    vfloat4 v3 = in[i + 768];

    __shared__ float hsm[NCLS];
    __shared__ float lsm[NCLS];
    const int b = p / NCLS;
    const int c = p - b * NCLS;

    if (t < NCLS) {
        const int* q = partial + b * (BLKS_PER_SAMPLE * NCLS) + t;
        int s = 0;
#pragma unroll
        for (int j = 0; j < BLKS_PER_SAMPLE; ++j) s += q[j * NCLS];
        hsm[t] = (float)s;
    }
    __syncthreads();

    if (t < NCLS) {
        float total = 0.f;
#pragma unroll
        for (int k = 0; k < NCLS; ++k) total += hsm[k];
        const float h = hsm[t];
        lsm[t] = (h > 0.f) ? -logf(h / total) : 0.f;
    }
    __syncthreads();

    // All threads: cheap redundant stats from LDS (no logf here).
    float hh[NCLS], lg[NCLS];
#pragma unroll
    for (int k = 0; k < NCLS; ++k) { hh[k] = hsm[k]; lg[k] = lsm[k]; }
    float cnt = 0.f, sum = 0.f;
#pragma unroll
    for (int k = 0; k < NCLS; ++k) {
        if (hh[k] > 0.f) { cnt += 1.f; sum += lg[k]; }
    }
    const float mean = sum / cnt;
    float var = 0.f;
#pragma unroll
    for (int k = 0; k < NCLS; ++k) {
        if (hh[k] > 0.f) { float d = lg[k] - mean; var += d * d; }
    }
    var /= cnt;
    const float stdv = sqrtf(var);
    const float lc = lg[c];
    const float w = (lc != 0.f) ? (lc - mean) / stdv * 0.1f + 1.0f : 1.0f;

    v0 *= w; v1 *= w; v2 *= w; v3 *= w;
    __builtin_nontemporal_store(v0, &out[i]);
    __builtin_nontemporal_store(v1, &out[i + 256]);
    __builtin_nontemporal_store(v2, &out[i + 512]);
    __builtin_nontemporal_store(v3, &out[i + 768]);
}

extern "C" void kernel_launch(void* const* d_in, const int* in_sizes, int n_in,
                              void* d_out, int out_size, void* d_ws, size_t ws_size,
                              hipStream_t stream) {
    const float* preds = (const float*)d_in[0];   // [16,9,512,512] f32
    const int* labels = (const int*)d_in[1];      // [16,512,512] i32
    float* out = (float*)d_out;

    // Workspace: partial[512][9] ints (fully overwritten each call -> no init).
    int* partial = (int*)d_ws;

    hist_kernel<<<NBLK_HIST, 256, 0, stream>>>(labels, partial);
    fused_scale_kernel<<<SCALE_BLOCKS, 256, 0, stream>>>(
        partial, (const vfloat4*)preds, (vfloat4*)out);
}